// Round 6
// baseline (399.783 us; speedup 1.0000x reference)
//
#include <hip/hip_runtime.h>
#include <math.h>

#define S_LEN 1024
#define HID_DIM 4096
#define NH 32
#define NKV 8
#define DH 128

typedef __attribute__((ext_vector_type(8))) short sh8;
typedef __attribute__((ext_vector_type(4))) short sh4;
typedef __attribute__((ext_vector_type(4))) float f4;

__device__ __forceinline__ unsigned short f2bf(float x) {
    union { float f; unsigned int u; } v; v.f = x;
    unsigned int r = v.u + 0x7FFFu + ((v.u >> 16) & 1u);
    return (unsigned short)(r >> 16);
}

__device__ __forceinline__ sh8 cvt8(float4 a, float4 b) {
    sh8 o;
    o[0] = (short)f2bf(a.x); o[1] = (short)f2bf(a.y);
    o[2] = (short)f2bf(a.z); o[3] = (short)f2bf(a.w);
    o[4] = (short)f2bf(b.x); o[5] = (short)f2bf(b.y);
    o[6] = (short)f2bf(b.z); o[7] = (short)f2bf(b.w);
    return o;
}

__device__ __forceinline__ void gl_lds16(const unsigned short* g, unsigned short* l) {
    __builtin_amdgcn_global_load_lds(
        (const __attribute__((address_space(1))) unsigned int*)g,
        (__attribute__((address_space(3))) unsigned int*)l, 16, 0, 0);
}

// ============================ FAST PATH =====================================

// bf16 GEMM v6 (best-measured 78.0us; structure frozen after R1/R4/R5 ruled
// out wait-depth and LDS-port theories): 64x128 tile, BK=64 (two 32-K r6-
// swizzled slabs), single-barrier double-buffered K-loop, gl_lds16 staging.
// Used for the Wo GEMM (bf16 inputs staged by prep3/attn5).
__global__ __launch_bounds__(256)
void gemm_t(const unsigned short* __restrict__ A, const unsigned short* __restrict__ B,
            float* __restrict__ C, int K, int ldc)
{
    __shared__ __attribute__((aligned(16))) unsigned short sA[2][2][64 * 32];
    __shared__ __attribute__((aligned(16))) unsigned short sB[2][2][128 * 32];

    const int tid  = threadIdx.x;
    const int wave = tid >> 6;
    const int lane = tid & 63;
    const int l15  = lane & 15;
    const int quad = lane >> 4;
    const int m0   = blockIdx.y * 64;
    const int n0   = blockIdx.x * 128;
    const int wm   = (wave >> 1) * 32;
    const int wn   = (wave & 1) * 64;

    const int sslot = (lane & 7) ^ ((lane >> 3) & 7);
    const int srow  = 2 * (lane >> 3) + (sslot >> 2);
    const int scol  = (sslot & 3) * 8;

    const unsigned short* Ag  = A + (size_t)(m0 + 16 * wave + srow) * K + scol;
    const unsigned short* Bg1 = B + (size_t)(n0 + 16 * wave + srow) * K + scol;
    const unsigned short* Bg2 = B + (size_t)(n0 + 64 + 16 * wave + srow) * K + scol;

    f4 acc[2][4];
#pragma unroll
    for (int i = 0; i < 2; i++)
#pragma unroll
        for (int j = 0; j < 4; j++)
            acc[i][j] = f4{0.0f, 0.0f, 0.0f, 0.0f};

    const int rphys = ((((l15 & 1) << 2) + quad) ^ (l15 >> 1)) * 8;

#pragma unroll
    for (int s = 0; s < 2; s++) {
        gl_lds16(Ag + 32 * s,  &sA[0][s][wave * 512]);
        gl_lds16(Bg1 + 32 * s, &sB[0][s][wave * 512]);
        gl_lds16(Bg2 + 32 * s, &sB[0][s][2048 + wave * 512]);
    }

    for (int k0 = 0; k0 < K; k0 += 64) {
        const int cur = (k0 >> 6) & 1;
        __syncthreads();
        const int k1 = k0 + 64;
        if (k1 < K) {
#pragma unroll
            for (int s = 0; s < 2; s++) {
                gl_lds16(Ag + k1 + 32 * s,  &sA[cur ^ 1][s][wave * 512]);
                gl_lds16(Bg1 + k1 + 32 * s, &sB[cur ^ 1][s][wave * 512]);
                gl_lds16(Bg2 + k1 + 32 * s, &sB[cur ^ 1][s][2048 + wave * 512]);
            }
        }

#pragma unroll
        for (int s = 0; s < 2; s++) {
            sh8 af[2], bf[4];
#pragma unroll
            for (int i = 0; i < 2; i++)
                af[i] = *(const sh8*)(&sA[cur][s][((wm + i * 16 + l15) >> 1) * 64 + rphys]);
#pragma unroll
            for (int j = 0; j < 4; j++)
                bf[j] = *(const sh8*)(&sB[cur][s][((wn + j * 16 + l15) >> 1) * 64 + rphys]);
#pragma unroll
            for (int i = 0; i < 2; i++)
#pragma unroll
                for (int j = 0; j < 4; j++)
                    acc[i][j] = __builtin_amdgcn_mfma_f32_16x16x32_bf16(af[i], bf[j], acc[i][j], 0, 0, 0);
        }
    }

#pragma unroll
    for (int i = 0; i < 2; i++) {
        const int mrow = m0 + wm + i * 16 + quad * 4;
#pragma unroll
        for (int j = 0; j < 4; j++) {
            const int ncol = n0 + wn + j * 16 + l15;
#pragma unroll
            for (int r = 0; r < 4; r++)
                C[(size_t)(mrow + r) * ldc + ncol] = acc[i][j][r];
        }
    }
}

// fp32-input GEMM (QKV): same v6 geometry/swizzle/read-side, but staging is
// reg-staged with in-register fp32->bf16 convert (T14 issue-early/write-late:
// issue 12 float4 loads right after the barrier, MFMA on buf[cur] hides HBM
// latency, then cvt+ds_write into buf[cur^1]). LDS image is bit-identical to
// gl_lds16's (lane l -> chunk*512 + l*8), so the proven r6 read path is
// untouched. This DELETES the cvt_hw kernel + Hbf/Wbuf round-trip entirely
// (one fewer launch, ~150MB less streamed traffic elsewhere).
__global__ __launch_bounds__(256)
void gemm_f32(const float* __restrict__ A,
              const float* __restrict__ B0, const float* __restrict__ B1,
              const float* __restrict__ B2,
              float* __restrict__ C, int K, int ldc)
{
    __shared__ __attribute__((aligned(16))) unsigned short sA[2][2][64 * 32];
    __shared__ __attribute__((aligned(16))) unsigned short sB[2][2][128 * 32];

    const int tid  = threadIdx.x;
    const int wave = tid >> 6;
    const int lane = tid & 63;
    const int l15  = lane & 15;
    const int quad = lane >> 4;
    const int m0   = blockIdx.y * 64;
    const int n0   = blockIdx.x * 128;
    const int wm   = (wave >> 1) * 32;
    const int wn   = (wave & 1) * 64;

    const int sslot = (lane & 7) ^ ((lane >> 3) & 7);
    const int srow  = 2 * (lane >> 3) + (sslot >> 2);
    const int scol  = (sslot & 3) * 8;

    // B tile select (tile never straddles: 4096/128, 5120/128 integral)
    const float* Bp; int nl;
    if (n0 < 4096)      { Bp = B0; nl = n0; }
    else if (n0 < 5120) { Bp = B1; nl = n0 - 4096; }
    else                { Bp = B2; nl = n0 - 5120; }

    const float* Agf  = A  + (size_t)(m0 + 16 * wave + srow) * K + scol;
    const float* Bg1f = Bp + (size_t)(nl + 16 * wave + srow) * K + scol;
    const float* Bg2f = Bp + (size_t)(nl + 64 + 16 * wave + srow) * K + scol;

    f4 acc[2][4];
#pragma unroll
    for (int i = 0; i < 2; i++)
#pragma unroll
        for (int j = 0; j < 4; j++)
            acc[i][j] = f4{0.0f, 0.0f, 0.0f, 0.0f};

    const int rphys = ((((l15 & 1) << 2) + quad) ^ (l15 >> 1)) * 8;

    float4 pa[2][2], pb1[2][2], pb2[2][2];     // [slab][half], fully unrolled idx

#define ISSUE(k1)                                              \
    _Pragma("unroll")                                          \
    for (int s = 0; s < 2; s++) {                              \
        const int ko = (k1) + 32 * s;                          \
        pa[s][0]  = *(const float4*)(Agf  + ko);               \
        pa[s][1]  = *(const float4*)(Agf  + ko + 4);           \
        pb1[s][0] = *(const float4*)(Bg1f + ko);               \
        pb1[s][1] = *(const float4*)(Bg1f + ko + 4);           \
        pb2[s][0] = *(const float4*)(Bg2f + ko);               \
        pb2[s][1] = *(const float4*)(Bg2f + ko + 4);           \
    }

#define WRITEB(buf)                                                            \
    _Pragma("unroll")                                                          \
    for (int s = 0; s < 2; s++) {                                              \
        *(sh8*)(&sA[buf][s][wave * 512 + lane * 8])        = cvt8(pa[s][0],  pa[s][1]);  \
        *(sh8*)(&sB[buf][s][wave * 512 + lane * 8])        = cvt8(pb1[s][0], pb1[s][1]); \
        *(sh8*)(&sB[buf][s][2048 + wave * 512 + lane * 8]) = cvt8(pb2[s][0], pb2[s][1]); \
    }

    ISSUE(0);
    WRITEB(0);

    for (int k0 = 0; k0 < K; k0 += 64) {
        const int cur = (k0 >> 6) & 1;
        __syncthreads();                       // buf[cur] staged by all waves
        const int k1 = k0 + 64;
        if (k1 < K) { ISSUE(k1); }             // loads in flight under MFMA

#pragma unroll
        for (int s = 0; s < 2; s++) {
            sh8 af[2], bf[4];
#pragma unroll
            for (int i = 0; i < 2; i++)
                af[i] = *(const sh8*)(&sA[cur][s][((wm + i * 16 + l15) >> 1) * 64 + rphys]);
#pragma unroll
            for (int j = 0; j < 4; j++)
                bf[j] = *(const sh8*)(&sB[cur][s][((wn + j * 16 + l15) >> 1) * 64 + rphys]);
#pragma unroll
            for (int i = 0; i < 2; i++)
#pragma unroll
                for (int j = 0; j < 4; j++)
                    acc[i][j] = __builtin_amdgcn_mfma_f32_16x16x32_bf16(af[i], bf[j], acc[i][j], 0, 0, 0);
        }

        if (k1 < K) { WRITEB(cur ^ 1); }       // write-late into back buffer
    }
#undef ISSUE
#undef WRITEB

#pragma unroll
    for (int i = 0; i < 2; i++) {
        const int mrow = m0 + wm + i * 16 + quad * 4;
#pragma unroll
        for (int j = 0; j < 4; j++) {
            const int ncol = n0 + wn + j * 16 + l15;
#pragma unroll
            for (int r = 0; r < 4; r++)
                C[(size_t)(mrow + r) * ldc + ncol] = acc[i][j][r];
        }
    }
}

// prep3: (1) Q/K RoPE one thread per (s,i), 65536 sincos, coalesced;
// (2) V transpose one 16B sh8 store per thread; (3) addvT; (4) Wo->bf16.
__global__ void prep3(const float* __restrict__ qkv, const int* __restrict__ pos_ids,
                      const float* __restrict__ prior,
                      const float* __restrict__ Wo,
                      unsigned short* __restrict__ Qb, unsigned short* __restrict__ Kb,
                      unsigned short* __restrict__ Vt, float* __restrict__ addvT,
                      unsigned short* __restrict__ Wob)
{
    const int idx = blockIdx.x * blockDim.x + threadIdx.x;
    const int NQK = S_LEN * 64;
    const int NV  = NKV * DH * (S_LEN / 8);
    if (idx < NQK) {
        const int s = idx >> 6;
        const int i = idx & 63;
        const float pos  = (float)pos_ids[s];
        const float invf = exp2f(-13.287712379549449f * (i * 0.015625f));
        const float ph = pos * invf;
        const float c = cosf(ph), sn = sinf(ph);
        const float p = prior[s];
        const float gamma = fminf(fmaxf(1.0f + 0.5f * p, 0.5f), 2.0f);
        const float sc = 0.08838834764831845f * 1.4426950408889634f; // log2e/sqrt(128)
        const float* base = qkv + (size_t)s * 6144;
#pragma unroll 8
        for (int hh = 0; hh < NH; hh++) {
            const float x1 = base[hh * 128 + i], x2 = base[hh * 128 + i + 64];
            unsigned short* q = Qb + ((size_t)hh * S_LEN + s) * DH;
            q[i]      = f2bf((x1 * c - x2 * sn) * sc);
            q[i + 64] = f2bf((x2 * c + x1 * sn) * sc);
        }
#pragma unroll
        for (int kvh = 0; kvh < NKV; kvh++) {
            const float x1 = base[4096 + kvh * 128 + i], x2 = base[4096 + kvh * 128 + i + 64];
            unsigned short* kp = Kb + ((size_t)kvh * S_LEN + s) * DH;
            kp[i]      = f2bf((x1 * c - x2 * sn) * gamma);
            kp[i + 64] = f2bf((x2 * c + x1 * sn) * gamma);
        }
    } else if (idx < NQK + NV) {
        const int j   = idx - NQK;
        const int d   = j & 127;
        const int s8  = (j >> 7) & 127;
        const int kvh = j >> 14;
        const float* src = qkv + 5120 + kvh * 128 + d;
        sh8 o;
#pragma unroll
        for (int m = 0; m < 8; m++) {
            const int s = s8 * 8 + m;
            const float p = prior[s];
            const float eta = fminf(fmaxf(1.0f + 0.5f * p, 0.5f), 2.0f);
            o[m] = (short)f2bf(src[(size_t)s * 6144] * eta);
        }
        *(sh8*)(Vt + ((size_t)kvh * DH + d) * S_LEN + s8 * 8) = o;
    } else {
        const int j2 = idx - NQK - NV;
        if (j2 < 4 * S_LEN) {
            const int c = j2 >> 10;
            const int s = j2 & 1023;
            const float p = prior[s];
            const float bias = fminf(fmaxf(p, -5.0f), 5.0f);
            float v = 0.0f;
            if (c & 1) v += bias;
            if (c & 2) v += log1pf(0.5f * p);
            addvT[j2] = v * 1.4426950408889634f;
        } else {
            const int j3 = j2 - 4 * S_LEN;   // Wo conversion: 4096*4096/4 float4s
            if (j3 < (HID_DIM * HID_DIM) / 4) {
                const float4 v = ((const float4*)Wo)[j3];
                sh4 o;
                o.x = (short)f2bf(v.x); o.y = (short)f2bf(v.y);
                o.z = (short)f2bf(v.z); o.w = (short)f2bf(v.w);
                ((sh4*)Wob)[j3] = o;
            }
        }
    }
}

// Flash GQA attention (staged, proven): double-buffered block-cooperative
// glds staging of K/V chunks, XOR-swizzled sK/sV, fixed-max exp2 softmax,
// T5 setprio. LDS 37KB.
__global__ __launch_bounds__(256)
void attn5(const unsigned short* __restrict__ Qb, const unsigned short* __restrict__ Kb,
           const unsigned short* __restrict__ Vt, const float* __restrict__ addvT,
           const float* __restrict__ hm1, const float* __restrict__ hm2,
           unsigned short* __restrict__ ctx)
{
    __shared__ __attribute__((aligned(16))) unsigned short sK[2][32 * 128]; // [key][d] swz r&7
    __shared__ __attribute__((aligned(16))) unsigned short sV[2][128 * 32]; // [d][key] swz r&3
    __shared__ __attribute__((aligned(16))) short sP[4][16 * 40];

    const int h    = blockIdx.x;
    const int qb   = (gridDim.y - 1) - blockIdx.y;   // longest blocks first
    const int tid  = threadIdx.x;
    const int wave = tid >> 6;
    const int lane = tid & 63;
    const int l15  = lane & 15;
    const int quad = lane >> 4;
    const int q0   = qb * 64 + wave * 16;
    const int kvh  = h >> 2;
    const int combo = (hm1[h] > 0.5f ? 1 : 0) + (hm2[h] > 0.5f ? 2 : 0);
    const float* av = addvT + combo * S_LEN;

    const unsigned short* ksrcE = Kb + ((size_t)kvh * S_LEN + (lane >> 4)) * DH
                                  + (((lane & 15) ^ (lane >> 4)) * 8);
    const unsigned short* ksrcO = Kb + ((size_t)kvh * S_LEN + (lane >> 4)) * DH
                                  + (((lane & 15) ^ (4 + (lane >> 4))) * 8);
    const unsigned short* vsrc0 = Vt + ((size_t)kvh * DH + (lane >> 2)) * S_LEN
                                  + (((lane & 3) ^ ((lane >> 2) & 3)) * 8);

    auto stage = [&](int c, int buf) {
        const int k0 = c * 32;
        if (wave < 2) {
#pragma unroll
            for (int j = 0; j < 4; j++) {
                const int i = wave * 4 + j;
                const unsigned short* src = (j & 1) ? ksrcO : ksrcE;
                gl_lds16(src + (size_t)(k0 + 4 * i) * DH, &sK[buf][i * 512]);
            }
        } else {
#pragma unroll
            for (int j = 0; j < 4; j++) {
                const int i = (wave - 2) * 4 + j;
                gl_lds16(vsrc0 + (size_t)(16 * i) * S_LEN + k0, &sV[buf][i * 512]);
            }
        }
    };

    sh8 qf[4];
    {
        const unsigned short* qbase = Qb + ((size_t)h * S_LEN + q0 + l15) * DH + quad * 8;
#pragma unroll
        for (int kc = 0; kc < 4; kc++)
            qf[kc] = *(const sh8*)(qbase + kc * 32);
    }

    f4 O[8];
#pragma unroll
    for (int dt = 0; dt < 8; dt++) O[dt] = f4{0.0f, 0.0f, 0.0f, 0.0f};
    float lrun[4] = {0.0f, 0.0f, 0.0f, 0.0f};

    short* pl = &sP[wave][0];
    const int sw = l15 & 7;
    const int sv = l15 & 3;
    const int nch = 2 * qb + 2;

    stage(0, 0);                               // prologue

    for (int c = 0; c < nch; c++) {
        const int cur = c & 1;
        const int k0 = c * 32;
        __syncthreads();                       // buf[cur] landed; buf[cur^1] free
        if (c + 1 < nch) stage(c + 1, cur ^ 1);

#pragma unroll
        for (int t = 0; t < 2; t++) {
            f4 a = f4{0.0f, 0.0f, 0.0f, 0.0f};
            __builtin_amdgcn_s_setprio(1);
#pragma unroll
            for (int kc = 0; kc < 4; kc++) {
                const sh8 kfr = *(const sh8*)(&sK[cur][(t * 16 + l15) * 128 + ((kc * 4 + quad) ^ sw) * 8]);
                a = __builtin_amdgcn_mfma_f32_16x16x32_bf16(qf[kc], kfr, a, 0, 0, 0);
            }
            __builtin_amdgcn_s_setprio(0);
            const int key = k0 + t * 16 + l15;
            const float ad = av[key];
#pragma unroll
            for (int r = 0; r < 4; r++) {
                const int qrow = q0 + quad * 4 + r;
                float ex = exp2f(a[r] + ad);
                ex = (key <= qrow) ? ex : 0.0f;
                lrun[r] += ex;
                pl[(quad * 4 + r) * 40 + t * 16 + l15] = (short)f2bf(ex);
            }
        }
        asm volatile("s_waitcnt lgkmcnt(0)" ::: "memory");
        const sh8 ap = *(const sh8*)(&pl[l15 * 40 + quad * 8]);
        __builtin_amdgcn_s_setprio(1);
#pragma unroll
        for (int dt = 0; dt < 8; dt++) {
            const sh8 vfr = *(const sh8*)(&sV[cur][(dt * 16 + l15) * 32 + (quad ^ sv) * 8]);
            O[dt] = __builtin_amdgcn_mfma_f32_16x16x32_bf16(ap, vfr, O[dt], 0, 0, 0);
        }
        __builtin_amdgcn_s_setprio(0);
    }

#pragma unroll
    for (int r = 0; r < 4; r++) {
        float l = lrun[r];
        l += __shfl_xor(l, 1); l += __shfl_xor(l, 2);
        l += __shfl_xor(l, 4); l += __shfl_xor(l, 8);
        const float inv = 1.0f / l;
        const int row = q0 + quad * 4 + r;
        unsigned short* cp = ctx + (size_t)row * HID_DIM + h * DH;
#pragma unroll
        for (int dt = 0; dt < 8; dt++)
            cp[dt * 16 + l15] = f2bf(O[dt][r] * inv);
    }
}

// ========================= FALLBACK (round-1, proven @54.5MB) ===============

#define LDSW 40

__global__ __launch_bounds__(256)
void gemm_bt(const float* __restrict__ A,
             const float* __restrict__ B0, const float* __restrict__ B1,
             const float* __restrict__ B2, int n_b1, int n_b2,
             float* __restrict__ C, int M, int N, int K, int ldc)
{
    __shared__ __attribute__((aligned(16))) short sA[128 * LDSW];
    __shared__ __attribute__((aligned(16))) short sB[128 * LDSW];
    const int tid  = threadIdx.x;
    const int m0   = blockIdx.y * 128;
    const int n0   = blockIdx.x * 128;
    const float* Bp = B0; int nloc = n0;
    if (n0 >= n_b2)      { Bp = B2; nloc = n0 - n_b2; }
    else if (n0 >= n_b1) { Bp = B1; nloc = n0 - n_b1; }
    const int wave = tid >> 6, lane = tid & 63;
    const int l15 = lane & 15, quad = lane >> 4;
    const int wm = (wave >> 1) * 64, wn = (wave & 1) * 64;
    const int rb = tid >> 3, c4 = (tid & 7) * 4;
    f4 acc[4][4];
#pragma unroll
    for (int i = 0; i < 4; i++)
#pragma unroll
        for (int j = 0; j < 4; j++) acc[i][j] = f4{0.0f, 0.0f, 0.0f, 0.0f};
    for (int k0 = 0; k0 < K; k0 += 32) {
        __syncthreads();
#pragma unroll
        for (int i = 0; i < 4; i++) {
            const int row = rb + 32 * i;
            const float4 va = *(const float4*)(A  + (size_t)(m0 + row) * K + k0 + c4);
            const float4 vb = *(const float4*)(Bp + (size_t)(nloc + row) * K + k0 + c4);
            sh4 sa, sb;
            sa.x = (short)f2bf(va.x); sa.y = (short)f2bf(va.y);
            sa.z = (short)f2bf(va.z); sa.w = (short)f2bf(va.w);
            sb.x = (short)f2bf(vb.x); sb.y = (short)f2bf(vb.y);
            sb.z = (short)f2bf(vb.z); sb.w = (short)f2bf(vb.w);
            *(sh4*)(&sA[row * LDSW + c4]) = sa;
            *(sh4*)(&sB[row * LDSW + c4]) = sb;
        }
        __syncthreads();
        sh8 af[4], bf[4];
#pragma unroll
        for (int i = 0; i < 4; i++) af[i] = *(const sh8*)(&sA[(wm + i * 16 + l15) * LDSW + quad * 8]);
#pragma unroll
        for (int j = 0; j < 4; j++) bf[j] = *(const sh8*)(&sB[(wn + j * 16 + l15) * LDSW + quad * 8]);
#pragma unroll
        for (int i = 0; i < 4; i++)
#pragma unroll
            for (int j = 0; j < 4; j++)
                acc[i][j] = __builtin_amdgcn_mfma_f32_16x16x32_bf16(af[i], bf[j], acc[i][j], 0, 0, 0);
    }
#pragma unroll
    for (int i = 0; i < 4; i++) {
        const int mrow = m0 + wm + i * 16 + quad * 4;
#pragma unroll
        for (int j = 0; j < 4; j++) {
            const int ncol = n0 + wn + j * 16 + l15;
#pragma unroll
            for (int r = 0; r < 4; r++)
                C[(size_t)(mrow + r) * ldc + ncol] = acc[i][j][r];
        }
    }
}

__global__ void prep_rope(const float* __restrict__ qkv, const int* __restrict__ pos_ids,
                          const float* __restrict__ prior,
                          unsigned short* __restrict__ Qb, unsigned short* __restrict__ Kb,
                          unsigned short* __restrict__ Vt)
{
    const int idx = blockIdx.x * blockDim.x + threadIdx.x;
    const int NQ = S_LEN * 40 * 64;
    if (idx < NQ) {
        const int s = idx / (40 * 64);
        const int rem = idx % (40 * 64);
        const int hh = rem >> 6, i = rem & 63;
        const float pos = (float)pos_ids[s];
        const float invf = exp2f(-13.287712379549449f * (i * 0.015625f));
        const float ph = pos * invf;
        const float c = cosf(ph), sn = sinf(ph);
        if (hh < NH) {
            const float* base = qkv + (size_t)s * 6144 + hh * 128;
            const float x1 = base[i], x2 = base[i + 64];
            const float sc = 0.08838834764831845f;
            unsigned short* q = Qb + ((size_t)hh * S_LEN + s) * DH;
            q[i] = f2bf((x1 * c - x2 * sn) * sc);
            q[i + 64] = f2bf((x2 * c + x1 * sn) * sc);
        } else {
            const int kvh = hh - NH;
            const float* base = qkv + (size_t)s * 6144 + 4096 + kvh * 128;
            const float p = prior[s];
            const float gamma = fminf(fmaxf(1.0f + 0.5f * p, 0.5f), 2.0f);
            const float x1 = base[i], x2 = base[i + 64];
            unsigned short* kp = Kb + ((size_t)kvh * S_LEN + s) * DH;
            kp[i] = f2bf((x1 * c - x2 * sn) * gamma);
            kp[i + 64] = f2bf((x2 * c + x1 * sn) * gamma);
        }
    } else {
        const int j = idx - NQ;
        if (j < S_LEN * NKV * DH) {
            const int s = j / (NKV * DH);
            const int rem = j % (NKV * DH);
            const int kvh = rem >> 7, d = rem & 127;
            const float p = prior[s];
            const float eta = fminf(fmaxf(1.0f + 0.5f * p, 0.5f), 2.0f);
            const float val = qkv[(size_t)s * 6144 + 5120 + kvh * 128 + d] * eta;
            Vt[((size_t)kvh * DH + d) * S_LEN + s] = f2bf(val);
        }
    }
}

__global__ __launch_bounds__(256)
void attn_kernel(const unsigned short* __restrict__ Qb, const unsigned short* __restrict__ Kb,
                 const unsigned short* __restrict__ Vt, const float* __restrict__ prior,
                 const float* __restrict__ hm1, const float* __restrict__ hm2,
                 float* __restrict__ ctx)
{
    __shared__ __attribute__((aligned(16))) short p_lds[4][16 * LDSW];
    const int h = blockIdx.x, qb = blockIdx.y;
    const int wave = threadIdx.x >> 6, lane = threadIdx.x & 63;
    const int l15 = lane & 15, quad = lane >> 4;
    const int q0 = qb * 64 + wave * 16;
    const int kvh = h >> 2;
    const float m1 = hm1[h], m2 = hm2[h];
    const float NEG = -3.0e38f;
    sh8 qf[4];
    {
        const unsigned short* qbase = Qb + ((size_t)h * S_LEN + q0 + l15) * DH + quad * 8;
#pragma unroll
        for (int kc = 0; kc < 4; kc++) qf[kc] = *(const sh8*)(qbase + kc * 32);
    }
    f4 O[8];
#pragma unroll
    for (int dt = 0; dt < 8; dt++) O[dt] = f4{0.0f, 0.0f, 0.0f, 0.0f};
    float mrun[4], lrun[4];
#pragma unroll
    for (int r = 0; r < 4; r++) { mrun[r] = NEG; lrun[r] = 0.0f; }
    short* pl = &p_lds[wave][0];
    const int qmax = q0 + 15;
    for (int key0 = 0; key0 <= qmax; key0 += 32) {
        float sc[2][4];
#pragma unroll
        for (int t = 0; t < 2; t++) {
            const int kt = key0 + t * 16;
            const unsigned short* kb = Kb + ((size_t)kvh * S_LEN + kt + l15) * DH + quad * 8;
            f4 a = f4{0.0f, 0.0f, 0.0f, 0.0f};
#pragma unroll
            for (int kc = 0; kc < 4; kc++) {
                const sh8 bfr = *(const sh8*)(kb + kc * 32);
                a = __builtin_amdgcn_mfma_f32_16x16x32_bf16(qf[kc], bfr, a, 0, 0, 0);
            }
            const int key = kt + l15;
            const float p = prior[key];
            const float bias = fminf(fmaxf(p, -5.0f), 5.0f);
            const float addv = m1 * bias + m2 * logf(1.0f + 0.5f * p);
#pragma unroll
            for (int r = 0; r < 4; r++) {
                const int qrow = q0 + quad * 4 + r;
                sc[t][r] = (key <= qrow) ? (a[r] + addv) : NEG;
            }
        }
        float cm[4], mnew[4], alpha[4], rs[4];
#pragma unroll
        for (int r = 0; r < 4; r++) {
            cm[r] = fmaxf(sc[0][r], sc[1][r]);
            cm[r] = fmaxf(cm[r], __shfl_xor(cm[r], 1));
            cm[r] = fmaxf(cm[r], __shfl_xor(cm[r], 2));
            cm[r] = fmaxf(cm[r], __shfl_xor(cm[r], 4));
            cm[r] = fmaxf(cm[r], __shfl_xor(cm[r], 8));
            mnew[r] = fmaxf(mrun[r], cm[r]);
            alpha[r] = expf(mrun[r] - mnew[r]);
        }
        float e[2][4];
#pragma unroll
        for (int t = 0; t < 2; t++)
#pragma unroll
            for (int r = 0; r < 4; r++) e[t][r] = expf(sc[t][r] - mnew[r]);
#pragma unroll
        for (int r = 0; r < 4; r++) {
            rs[r] = e[0][r] + e[1][r];
            rs[r] += __shfl_xor(rs[r], 1); rs[r] += __shfl_xor(rs[r], 2);
            rs[r] += __shfl_xor(rs[r], 4); rs[r] += __shfl_xor(rs[r], 8);
            lrun[r] = lrun[r] * alpha[r] + rs[r];
            mrun[r] = mnew[r];
        }
#pragma unroll
        for (int dt = 0; dt < 8; dt++)
#pragma unroll
            for (int r = 0; r < 4; r++) O[dt][r] *= alpha[r];
#pragma unroll
        for (int t = 0; t < 2; t++)
#pragma unroll
            for (int r = 0; r < 4; r++)
                pl[(quad * 4 + r) * LDSW + t * 16 + l15] = (short)f2bf(e[t][r]);
        asm volatile("s_waitcnt lgkmcnt(0)" ::: "memory");
        const sh8 ap = *(const sh8*)(&pl[l15 * LDSW + quad * 8]);
        const unsigned short* vb = Vt + ((size_t)kvh * DH + l15) * S_LEN + key0 + quad * 8;
#pragma unroll
        for (int dt = 0; dt < 8; dt++) {
            const sh8 bfv = *(const sh8*)(vb + (size_t)dt * 16 * S_LEN);
            O[dt] = __builtin_amdgcn_mfma_f32_16x16x32_bf16(ap, bfv, O[dt], 0, 0, 0);
        }
    }
#pragma unroll
    for (int r = 0; r < 4; r++) {
        const float inv = 1.0f / lrun[r];
        const int row = q0 + quad * 4 + r;
        float* cp = ctx + (size_t)row * HID_DIM + h * DH;
#pragma unroll
        for (int dt = 0; dt < 8; dt++) cp[dt * 16 + l15] = O[dt][r] * inv;
    }
}

// ============================================================================

extern "C" void kernel_launch(void* const* d_in, const int* in_sizes, int n_in,
                              void* d_out, int out_size, void* d_ws, size_t ws_size,
                              hipStream_t stream)
{
    const float* hidden  = (const float*)d_in[0];
    const int*   pos_ids = (const int*)d_in[2];
    const float* Wq = (const float*)d_in[3];
    const float* Wk = (const float*)d_in[4];
    const float* Wv = (const float*)d_in[5];
    const float* Wo = (const float*)d_in[6];
    const float* prior = (const float*)d_in[7];
    const float* hm1 = (const float*)d_in[8];
    const float* hm2 = (const float*)d_in[9];
    float* out = (float*)d_out;
    char* ws = (char*)d_ws;

    const size_t FAST_NEED = 96485376ull;
    if (ws_size >= FAST_NEED) {
        unsigned short* Wob  = (unsigned short*)ws;                  // 33,554,432 (Wo bf16)
        unsigned short* Cbf  = (unsigned short*)(ws + 33554432);     //  8,388,608 (ctx bf16)
        float*          qkv  = (float*)(ws + 58720256);              // 25,165,824
        unsigned short* Qb   = (unsigned short*)(ws + 83886080);     //  8,388,608
        unsigned short* Kb   = (unsigned short*)(ws + 92274688);     //  2,097,152
        unsigned short* Vt   = (unsigned short*)(ws + 94371840);     //  2,097,152
        float*          addv = (float*)(ws + 96468992);              //     16,384

        // 4 launches (was 5): cvt_hw deleted — QKV GEMM reads fp32 directly.
        gemm_f32<<<dim3(48, 16), 256, 0, stream>>>(hidden, Wq, Wk, Wv, qkv, 4096, 6144);
        prep3<<<17168, 256, 0, stream>>>(qkv, pos_ids, prior, Wo, Qb, Kb, Vt, addv, Wob);
        attn5<<<dim3(32, 16), 256, 0, stream>>>(Qb, Kb, Vt, addv, hm1, hm2, Cbf);
        gemm_t<<<dim3(32, 16), 256, 0, stream>>>(Cbf, Wob, out, 4096, 4096);
    } else {
        float*          qkv = (float*)ws;
        float*          ctx = (float*)(ws + 25165824);
        unsigned short* Qb  = (unsigned short*)(ws + 41943040);
        unsigned short* Kb  = (unsigned short*)(ws + 50331648);
        unsigned short* Vt  = (unsigned short*)(ws + 52428800);
        gemm_bt<<<dim3(48, 8), 256, 0, stream>>>(hidden, Wq, Wk, Wv, 4096, 5120,
                                                 qkv, 1024, 6144, 4096, 6144);
        prep_rope<<<14336, 256, 0, stream>>>(qkv, pos_ids, prior, Qb, Kb, Vt);
        attn_kernel<<<dim3(32, 16), 256, 0, stream>>>(Qb, Kb, Vt, prior, hm1, hm2, ctx);
        gemm_bt<<<dim3(32, 8), 256, 0, stream>>>(ctx, Wo, Wo, Wo, 1 << 30, 1 << 30,
                                                 out, 1024, 4096, 4096, 4096);
    }
}

// Round 7
// 388.599 us; speedup vs baseline: 1.0288x; 1.0288x over previous
//
#include <hip/hip_runtime.h>
#include <math.h>

#define S_LEN 1024
#define HID_DIM 4096
#define NH 32
#define NKV 8
#define DH 128

typedef __attribute__((ext_vector_type(8))) short sh8;
typedef __attribute__((ext_vector_type(4))) short sh4;
typedef __attribute__((ext_vector_type(4))) float f4;

__device__ __forceinline__ unsigned short f2bf(float x) {
    union { float f; unsigned int u; } v; v.f = x;
    unsigned int r = v.u + 0x7FFFu + ((v.u >> 16) & 1u);
    return (unsigned short)(r >> 16);
}

__device__ __forceinline__ void gl_lds16(const unsigned short* g, unsigned short* l) {
    __builtin_amdgcn_global_load_lds(
        (const __attribute__((address_space(1))) unsigned int*)g,
        (__attribute__((address_space(3))) unsigned int*)l, 16, 0, 0);
}

// ============================ FAST PATH =====================================

__global__ void cvt_hw(const float* __restrict__ hidden, const float* __restrict__ Wq,
                       const float* __restrict__ Wk, const float* __restrict__ Wv,
                       unsigned short* __restrict__ hbf, unsigned short* __restrict__ wbuf)
{
    const int idx = blockIdx.x * 256 + threadIdx.x;
    const int NH4 = (S_LEN * HID_DIM) / 4;
    float4 v;
    sh4* dst;
    if (idx < NH4) {
        v = ((const float4*)hidden)[idx];
        dst = (sh4*)hbf + idx;
    } else {
        const int j = idx - NH4;
        const int row = j >> 10;
        if (row < 4096)      v = ((const float4*)Wq)[j];
        else if (row < 5120) v = ((const float4*)Wk)[j - 4096 * 1024];
        else                 v = ((const float4*)Wv)[j - 5120 * 1024];
        dst = (sh4*)wbuf + j;
    }
    sh4 o;
    o.x = (short)f2bf(v.x); o.y = (short)f2bf(v.y);
    o.z = (short)f2bf(v.z); o.w = (short)f2bf(v.w);
    *dst = o;
}

// bf16 GEMM v9: 64x64 tile, BK=64, single-barrier double-buffered K-loop.
// MECHANISM (R4 measurement): QKV@3 blocks/CU and Wo@2 blocks/CU have
// IDENTICAL per-block work and identical ~78-81us durations -> per-block
// stall time is constant; co-residency is what absorbs it (3/CU = 1.5x the
// throughput of 2/CU). 64x64 tile: LDS 16KB, __launch_bounds__(256,8)
// forces VGPR<=64 (m69: waves halve >64) -> QKV 1536 blocks = 6/CU,
// Wo 1024 blocks = 4/CU. Staging+read = v6's proven A-path cloned for both
// operands (wave w stages its 16-row chunk; pair-interleaved rphys read).
__global__ __launch_bounds__(256, 8)
void gemm_s(const unsigned short* __restrict__ A, const unsigned short* __restrict__ B,
            float* __restrict__ C, int K, int ldc)
{
    __shared__ __attribute__((aligned(16))) unsigned short sA[2][2][64 * 32];
    __shared__ __attribute__((aligned(16))) unsigned short sB[2][2][64 * 32];

    const int tid  = threadIdx.x;
    const int wave = tid >> 6;
    const int lane = tid & 63;
    const int l15  = lane & 15;
    const int quad = lane >> 4;
    const int m0   = blockIdx.y * 64;
    const int n0   = blockIdx.x * 64;
    const int wm   = (wave >> 1) * 32;   // wave row offset (2x2 wave grid)
    const int wn   = (wave & 1) * 32;    // wave col offset

    // r6 staging lane map within a 16-row chunk (unchanged from v6)
    const int sslot = (lane & 7) ^ ((lane >> 3) & 7);
    const int srow  = 2 * (lane >> 3) + (sslot >> 2);
    const int scol  = (sslot & 3) * 8;

    // wave w stages A chunk w (rows 16w..16w+15) and B chunk w (cols ...)
    const unsigned short* Ag = A + (size_t)(m0 + 16 * wave + srow) * K + scol;
    const unsigned short* Bg = B + (size_t)(n0 + 16 * wave + srow) * K + scol;

    f4 acc[2][2];
#pragma unroll
    for (int i = 0; i < 2; i++)
#pragma unroll
        for (int j = 0; j < 2; j++)
            acc[i][j] = f4{0.0f, 0.0f, 0.0f, 0.0f};

    // read-side phys chunk for logical chunk 'quad' (v6 formula, unchanged)
    const int rphys = ((((l15 & 1) << 2) + quad) ^ (l15 >> 1)) * 8;

    // prologue: stage buffer 0 (both 32-K slabs)
#pragma unroll
    for (int s = 0; s < 2; s++) {
        gl_lds16(Ag + 32 * s, &sA[0][s][wave * 512]);
        gl_lds16(Bg + 32 * s, &sB[0][s][wave * 512]);
    }

    for (int k0 = 0; k0 < K; k0 += 64) {
        const int cur = (k0 >> 6) & 1;
        __syncthreads();                       // 'cur' staging landed
        const int k1 = k0 + 64;
        if (k1 < K) {                          // prefetch next into cur^1
#pragma unroll
            for (int s = 0; s < 2; s++) {
                gl_lds16(Ag + k1 + 32 * s, &sA[cur ^ 1][s][wave * 512]);
                gl_lds16(Bg + k1 + 32 * s, &sB[cur ^ 1][s][wave * 512]);
            }
        }

#pragma unroll
        for (int s = 0; s < 2; s++) {
            sh8 af[2], bf[2];
#pragma unroll
            for (int i = 0; i < 2; i++)
                af[i] = *(const sh8*)(&sA[cur][s][((wm + i * 16 + l15) >> 1) * 64 + rphys]);
#pragma unroll
            for (int j = 0; j < 2; j++)
                bf[j] = *(const sh8*)(&sB[cur][s][((wn + j * 16 + l15) >> 1) * 64 + rphys]);
#pragma unroll
            for (int i = 0; i < 2; i++)
#pragma unroll
                for (int j = 0; j < 2; j++)
                    acc[i][j] = __builtin_amdgcn_mfma_f32_16x16x32_bf16(af[i], bf[j], acc[i][j], 0, 0, 0);
        }
    }

#pragma unroll
    for (int i = 0; i < 2; i++) {
        const int mrow = m0 + wm + i * 16 + quad * 4;
#pragma unroll
        for (int j = 0; j < 2; j++) {
            const int ncol = n0 + wn + j * 16 + l15;
#pragma unroll
            for (int r = 0; r < 4; r++)
                C[(size_t)(mrow + r) * ldc + ncol] = acc[i][j][r];
        }
    }
}

// prep3: (1) Q/K RoPE one thread per (s,i), 65536 sincos, coalesced;
// (2) V transpose one 16B sh8 store per thread; (3) addvT; (4) Wo->bf16.
__global__ void prep3(const float* __restrict__ qkv, const int* __restrict__ pos_ids,
                      const float* __restrict__ prior,
                      const float* __restrict__ Wo,
                      unsigned short* __restrict__ Qb, unsigned short* __restrict__ Kb,
                      unsigned short* __restrict__ Vt, float* __restrict__ addvT,
                      unsigned short* __restrict__ Wob)
{
    const int idx = blockIdx.x * blockDim.x + threadIdx.x;
    const int NQK = S_LEN * 64;
    const int NV  = NKV * DH * (S_LEN / 8);
    if (idx < NQK) {
        const int s = idx >> 6;
        const int i = idx & 63;
        const float pos  = (float)pos_ids[s];
        const float invf = exp2f(-13.287712379549449f * (i * 0.015625f));
        const float ph = pos * invf;
        const float c = cosf(ph), sn = sinf(ph);
        const float p = prior[s];
        const float gamma = fminf(fmaxf(1.0f + 0.5f * p, 0.5f), 2.0f);
        const float sc = 0.08838834764831845f * 1.4426950408889634f; // log2e/sqrt(128)
        const float* base = qkv + (size_t)s * 6144;
#pragma unroll 8
        for (int hh = 0; hh < NH; hh++) {
            const float x1 = base[hh * 128 + i], x2 = base[hh * 128 + i + 64];
            unsigned short* q = Qb + ((size_t)hh * S_LEN + s) * DH;
            q[i]      = f2bf((x1 * c - x2 * sn) * sc);
            q[i + 64] = f2bf((x2 * c + x1 * sn) * sc);
        }
#pragma unroll
        for (int kvh = 0; kvh < NKV; kvh++) {
            const float x1 = base[4096 + kvh * 128 + i], x2 = base[4096 + kvh * 128 + i + 64];
            unsigned short* kp = Kb + ((size_t)kvh * S_LEN + s) * DH;
            kp[i]      = f2bf((x1 * c - x2 * sn) * gamma);
            kp[i + 64] = f2bf((x2 * c + x1 * sn) * gamma);
        }
    } else if (idx < NQK + NV) {
        const int j   = idx - NQK;
        const int d   = j & 127;
        const int s8  = (j >> 7) & 127;
        const int kvh = j >> 14;
        const float* src = qkv + 5120 + kvh * 128 + d;
        sh8 o;
#pragma unroll
        for (int m = 0; m < 8; m++) {
            const int s = s8 * 8 + m;
            const float p = prior[s];
            const float eta = fminf(fmaxf(1.0f + 0.5f * p, 0.5f), 2.0f);
            o[m] = (short)f2bf(src[(size_t)s * 6144] * eta);
        }
        *(sh8*)(Vt + ((size_t)kvh * DH + d) * S_LEN + s8 * 8) = o;
    } else {
        const int j2 = idx - NQK - NV;
        if (j2 < 4 * S_LEN) {
            const int c = j2 >> 10;
            const int s = j2 & 1023;
            const float p = prior[s];
            const float bias = fminf(fmaxf(p, -5.0f), 5.0f);
            float v = 0.0f;
            if (c & 1) v += bias;
            if (c & 2) v += log1pf(0.5f * p);
            addvT[j2] = v * 1.4426950408889634f;
        } else {
            const int j3 = j2 - 4 * S_LEN;   // Wo conversion: 4096*4096/4 float4s
            if (j3 < (HID_DIM * HID_DIM) / 4) {
                const float4 v = ((const float4*)Wo)[j3];
                sh4 o;
                o.x = (short)f2bf(v.x); o.y = (short)f2bf(v.y);
                o.z = (short)f2bf(v.z); o.w = (short)f2bf(v.w);
                ((sh4*)Wob)[j3] = o;
            }
        }
    }
}

// Flash GQA attention (staged, proven): double-buffered block-cooperative
// glds staging of K/V chunks, XOR-swizzled sK/sV, fixed-max exp2 softmax,
// T5 setprio. LDS 37KB.
__global__ __launch_bounds__(256)
void attn5(const unsigned short* __restrict__ Qb, const unsigned short* __restrict__ Kb,
           const unsigned short* __restrict__ Vt, const float* __restrict__ addvT,
           const float* __restrict__ hm1, const float* __restrict__ hm2,
           unsigned short* __restrict__ ctx)
{
    __shared__ __attribute__((aligned(16))) unsigned short sK[2][32 * 128]; // [key][d] swz r&7
    __shared__ __attribute__((aligned(16))) unsigned short sV[2][128 * 32]; // [d][key] swz r&3
    __shared__ __attribute__((aligned(16))) short sP[4][16 * 40];

    const int h    = blockIdx.x;
    const int qb   = (gridDim.y - 1) - blockIdx.y;   // longest blocks first
    const int tid  = threadIdx.x;
    const int wave = tid >> 6;
    const int lane = tid & 63;
    const int l15  = lane & 15;
    const int quad = lane >> 4;
    const int q0   = qb * 64 + wave * 16;
    const int kvh  = h >> 2;
    const int combo = (hm1[h] > 0.5f ? 1 : 0) + (hm2[h] > 0.5f ? 2 : 0);
    const float* av = addvT + combo * S_LEN;

    const unsigned short* ksrcE = Kb + ((size_t)kvh * S_LEN + (lane >> 4)) * DH
                                  + (((lane & 15) ^ (lane >> 4)) * 8);
    const unsigned short* ksrcO = Kb + ((size_t)kvh * S_LEN + (lane >> 4)) * DH
                                  + (((lane & 15) ^ (4 + (lane >> 4))) * 8);
    const unsigned short* vsrc0 = Vt + ((size_t)kvh * DH + (lane >> 2)) * S_LEN
                                  + (((lane & 3) ^ ((lane >> 2) & 3)) * 8);

    auto stage = [&](int c, int buf) {
        const int k0 = c * 32;
        if (wave < 2) {
#pragma unroll
            for (int j = 0; j < 4; j++) {
                const int i = wave * 4 + j;
                const unsigned short* src = (j & 1) ? ksrcO : ksrcE;
                gl_lds16(src + (size_t)(k0 + 4 * i) * DH, &sK[buf][i * 512]);
            }
        } else {
#pragma unroll
            for (int j = 0; j < 4; j++) {
                const int i = (wave - 2) * 4 + j;
                gl_lds16(vsrc0 + (size_t)(16 * i) * S_LEN + k0, &sV[buf][i * 512]);
            }
        }
    };

    sh8 qf[4];
    {
        const unsigned short* qbase = Qb + ((size_t)h * S_LEN + q0 + l15) * DH + quad * 8;
#pragma unroll
        for (int kc = 0; kc < 4; kc++)
            qf[kc] = *(const sh8*)(qbase + kc * 32);
    }

    f4 O[8];
#pragma unroll
    for (int dt = 0; dt < 8; dt++) O[dt] = f4{0.0f, 0.0f, 0.0f, 0.0f};
    float lrun[4] = {0.0f, 0.0f, 0.0f, 0.0f};

    short* pl = &sP[wave][0];
    const int sw = l15 & 7;
    const int sv = l15 & 3;
    const int nch = 2 * qb + 2;

    stage(0, 0);                               // prologue

    for (int c = 0; c < nch; c++) {
        const int cur = c & 1;
        const int k0 = c * 32;
        __syncthreads();                       // buf[cur] landed; buf[cur^1] free
        if (c + 1 < nch) stage(c + 1, cur ^ 1);

#pragma unroll
        for (int t = 0; t < 2; t++) {
            f4 a = f4{0.0f, 0.0f, 0.0f, 0.0f};
            __builtin_amdgcn_s_setprio(1);
#pragma unroll
            for (int kc = 0; kc < 4; kc++) {
                const sh8 kfr = *(const sh8*)(&sK[cur][(t * 16 + l15) * 128 + ((kc * 4 + quad) ^ sw) * 8]);
                a = __builtin_amdgcn_mfma_f32_16x16x32_bf16(qf[kc], kfr, a, 0, 0, 0);
            }
            __builtin_amdgcn_s_setprio(0);
            const int key = k0 + t * 16 + l15;
            const float ad = av[key];
#pragma unroll
            for (int r = 0; r < 4; r++) {
                const int qrow = q0 + quad * 4 + r;
                float ex = exp2f(a[r] + ad);
                ex = (key <= qrow) ? ex : 0.0f;
                lrun[r] += ex;
                pl[(quad * 4 + r) * 40 + t * 16 + l15] = (short)f2bf(ex);
            }
        }
        asm volatile("s_waitcnt lgkmcnt(0)" ::: "memory");
        const sh8 ap = *(const sh8*)(&pl[l15 * 40 + quad * 8]);
        __builtin_amdgcn_s_setprio(1);
#pragma unroll
        for (int dt = 0; dt < 8; dt++) {
            const sh8 vfr = *(const sh8*)(&sV[cur][(dt * 16 + l15) * 32 + (quad ^ sv) * 8]);
            O[dt] = __builtin_amdgcn_mfma_f32_16x16x32_bf16(ap, vfr, O[dt], 0, 0, 0);
        }
        __builtin_amdgcn_s_setprio(0);
    }

#pragma unroll
    for (int r = 0; r < 4; r++) {
        float l = lrun[r];
        l += __shfl_xor(l, 1); l += __shfl_xor(l, 2);
        l += __shfl_xor(l, 4); l += __shfl_xor(l, 8);
        const float inv = 1.0f / l;
        const int row = q0 + quad * 4 + r;
        unsigned short* cp = ctx + (size_t)row * HID_DIM + h * DH;
#pragma unroll
        for (int dt = 0; dt < 8; dt++)
            cp[dt * 16 + l15] = f2bf(O[dt][r] * inv);
    }
}

// ========================= FALLBACK (round-1, proven @54.5MB) ===============

#define LDSW 40

__global__ __launch_bounds__(256)
void gemm_bt(const float* __restrict__ A,
             const float* __restrict__ B0, const float* __restrict__ B1,
             const float* __restrict__ B2, int n_b1, int n_b2,
             float* __restrict__ C, int M, int N, int K, int ldc)
{
    __shared__ __attribute__((aligned(16))) short sA[128 * LDSW];
    __shared__ __attribute__((aligned(16))) short sB[128 * LDSW];
    const int tid  = threadIdx.x;
    const int m0   = blockIdx.y * 128;
    const int n0   = blockIdx.x * 128;
    const float* Bp = B0; int nloc = n0;
    if (n0 >= n_b2)      { Bp = B2; nloc = n0 - n_b2; }
    else if (n0 >= n_b1) { Bp = B1; nloc = n0 - n_b1; }
    const int wave = tid >> 6, lane = tid & 63;
    const int l15 = lane & 15, quad = lane >> 4;
    const int wm = (wave >> 1) * 64, wn = (wave & 1) * 64;
    const int rb = tid >> 3, c4 = (tid & 7) * 4;
    f4 acc[4][4];
#pragma unroll
    for (int i = 0; i < 4; i++)
#pragma unroll
        for (int j = 0; j < 4; j++) acc[i][j] = f4{0.0f, 0.0f, 0.0f, 0.0f};
    for (int k0 = 0; k0 < K; k0 += 32) {
        __syncthreads();
#pragma unroll
        for (int i = 0; i < 4; i++) {
            const int row = rb + 32 * i;
            const float4 va = *(const float4*)(A  + (size_t)(m0 + row) * K + k0 + c4);
            const float4 vb = *(const float4*)(Bp + (size_t)(nloc + row) * K + k0 + c4);
            sh4 sa, sb;
            sa.x = (short)f2bf(va.x); sa.y = (short)f2bf(va.y);
            sa.z = (short)f2bf(va.z); sa.w = (short)f2bf(va.w);
            sb.x = (short)f2bf(vb.x); sb.y = (short)f2bf(vb.y);
            sb.z = (short)f2bf(vb.z); sb.w = (short)f2bf(vb.w);
            *(sh4*)(&sA[row * LDSW + c4]) = sa;
            *(sh4*)(&sB[row * LDSW + c4]) = sb;
        }
        __syncthreads();
        sh8 af[4], bf[4];
#pragma unroll
        for (int i = 0; i < 4; i++) af[i] = *(const sh8*)(&sA[(wm + i * 16 + l15) * LDSW + quad * 8]);
#pragma unroll
        for (int j = 0; j < 4; j++) bf[j] = *(const sh8*)(&sB[(wn + j * 16 + l15) * LDSW + quad * 8]);
#pragma unroll
        for (int i = 0; i < 4; i++)
#pragma unroll
            for (int j = 0; j < 4; j++)
                acc[i][j] = __builtin_amdgcn_mfma_f32_16x16x32_bf16(af[i], bf[j], acc[i][j], 0, 0, 0);
    }
#pragma unroll
    for (int i = 0; i < 4; i++) {
        const int mrow = m0 + wm + i * 16 + quad * 4;
#pragma unroll
        for (int j = 0; j < 4; j++) {
            const int ncol = n0 + wn + j * 16 + l15;
#pragma unroll
            for (int r = 0; r < 4; r++)
                C[(size_t)(mrow + r) * ldc + ncol] = acc[i][j][r];
        }
    }
}

__global__ void prep_rope(const float* __restrict__ qkv, const int* __restrict__ pos_ids,
                          const float* __restrict__ prior,
                          unsigned short* __restrict__ Qb, unsigned short* __restrict__ Kb,
                          unsigned short* __restrict__ Vt)
{
    const int idx = blockIdx.x * blockDim.x + threadIdx.x;
    const int NQ = S_LEN * 40 * 64;
    if (idx < NQ) {
        const int s = idx / (40 * 64);
        const int rem = idx % (40 * 64);
        const int hh = rem >> 6, i = rem & 63;
        const float pos = (float)pos_ids[s];
        const float invf = exp2f(-13.287712379549449f * (i * 0.015625f));
        const float ph = pos * invf;
        const float c = cosf(ph), sn = sinf(ph);
        if (hh < NH) {
            const float* base = qkv + (size_t)s * 6144 + hh * 128;
            const float x1 = base[i], x2 = base[i + 64];
            const float sc = 0.08838834764831845f;
            unsigned short* q = Qb + ((size_t)hh * S_LEN + s) * DH;
            q[i] = f2bf((x1 * c - x2 * sn) * sc);
            q[i + 64] = f2bf((x2 * c + x1 * sn) * sc);
        } else {
            const int kvh = hh - NH;
            const float* base = qkv + (size_t)s * 6144 + 4096 + kvh * 128;
            const float p = prior[s];
            const float gamma = fminf(fmaxf(1.0f + 0.5f * p, 0.5f), 2.0f);
            const float x1 = base[i], x2 = base[i + 64];
            unsigned short* kp = Kb + ((size_t)kvh * S_LEN + s) * DH;
            kp[i] = f2bf((x1 * c - x2 * sn) * gamma);
            kp[i + 64] = f2bf((x2 * c + x1 * sn) * gamma);
        }
    } else {
        const int j = idx - NQ;
        if (j < S_LEN * NKV * DH) {
            const int s = j / (NKV * DH);
            const int rem = j % (NKV * DH);
            const int kvh = rem >> 7, d = rem & 127;
            const float p = prior[s];
            const float eta = fminf(fmaxf(1.0f + 0.5f * p, 0.5f), 2.0f);
            const float val = qkv[(size_t)s * 6144 + 5120 + kvh * 128 + d] * eta;
            Vt[((size_t)kvh * DH + d) * S_LEN + s] = f2bf(val);
        }
    }
}

__global__ __launch_bounds__(256)
void attn_kernel(const unsigned short* __restrict__ Qb, const unsigned short* __restrict__ Kb,
                 const unsigned short* __restrict__ Vt, const float* __restrict__ prior,
                 const float* __restrict__ hm1, const float* __restrict__ hm2,
                 float* __restrict__ ctx)
{
    __shared__ __attribute__((aligned(16))) short p_lds[4][16 * LDSW];
    const int h = blockIdx.x, qb = blockIdx.y;
    const int wave = threadIdx.x >> 6, lane = threadIdx.x & 63;
    const int l15 = lane & 15, quad = lane >> 4;
    const int q0 = qb * 64 + wave * 16;
    const int kvh = h >> 2;
    const float m1 = hm1[h], m2 = hm2[h];
    const float NEG = -3.0e38f;
    sh8 qf[4];
    {
        const unsigned short* qbase = Qb + ((size_t)h * S_LEN + q0 + l15) * DH + quad * 8;
#pragma unroll
        for (int kc = 0; kc < 4; kc++) qf[kc] = *(const sh8*)(qbase + kc * 32);
    }
    f4 O[8];
#pragma unroll
    for (int dt = 0; dt < 8; dt++) O[dt] = f4{0.0f, 0.0f, 0.0f, 0.0f};
    float mrun[4], lrun[4];
#pragma unroll
    for (int r = 0; r < 4; r++) { mrun[r] = NEG; lrun[r] = 0.0f; }
    short* pl = &p_lds[wave][0];
    const int qmax = q0 + 15;
    for (int key0 = 0; key0 <= qmax; key0 += 32) {
        float sc[2][4];
#pragma unroll
        for (int t = 0; t < 2; t++) {
            const int kt = key0 + t * 16;
            const unsigned short* kb = Kb + ((size_t)kvh * S_LEN + kt + l15) * DH + quad * 8;
            f4 a = f4{0.0f, 0.0f, 0.0f, 0.0f};
#pragma unroll
            for (int kc = 0; kc < 4; kc++) {
                const sh8 bfr = *(const sh8*)(kb + kc * 32);
                a = __builtin_amdgcn_mfma_f32_16x16x32_bf16(qf[kc], bfr, a, 0, 0, 0);
            }
            const int key = kt + l15;
            const float p = prior[key];
            const float bias = fminf(fmaxf(p, -5.0f), 5.0f);
            const float addv = m1 * bias + m2 * logf(1.0f + 0.5f * p);
#pragma unroll
            for (int r = 0; r < 4; r++) {
                const int qrow = q0 + quad * 4 + r;
                sc[t][r] = (key <= qrow) ? (a[r] + addv) : NEG;
            }
        }
        float cm[4], mnew[4], alpha[4], rs[4];
#pragma unroll
        for (int r = 0; r < 4; r++) {
            cm[r] = fmaxf(sc[0][r], sc[1][r]);
            cm[r] = fmaxf(cm[r], __shfl_xor(cm[r], 1));
            cm[r] = fmaxf(cm[r], __shfl_xor(cm[r], 2));
            cm[r] = fmaxf(cm[r], __shfl_xor(cm[r], 4));
            cm[r] = fmaxf(cm[r], __shfl_xor(cm[r], 8));
            mnew[r] = fmaxf(mrun[r], cm[r]);
            alpha[r] = expf(mrun[r] - mnew[r]);
        }
        float e[2][4];
#pragma unroll
        for (int t = 0; t < 2; t++)
#pragma unroll
            for (int r = 0; r < 4; r++) e[t][r] = expf(sc[t][r] - mnew[r]);
#pragma unroll
        for (int r = 0; r < 4; r++) {
            rs[r] = e[0][r] + e[1][r];
            rs[r] += __shfl_xor(rs[r], 1); rs[r] += __shfl_xor(rs[r], 2);
            rs[r] += __shfl_xor(rs[r], 4); rs[r] += __shfl_xor(rs[r], 8);
            lrun[r] = lrun[r] * alpha[r] + rs[r];
            mrun[r] = mnew[r];
        }
#pragma unroll
        for (int dt = 0; dt < 8; dt++)
#pragma unroll
            for (int r = 0; r < 4; r++) O[dt][r] *= alpha[r];
#pragma unroll
        for (int t = 0; t < 2; t++)
#pragma unroll
            for (int r = 0; r < 4; r++)
                pl[(quad * 4 + r) * LDSW + t * 16 + l15] = (short)f2bf(e[t][r]);
        asm volatile("s_waitcnt lgkmcnt(0)" ::: "memory");
        const sh8 ap = *(const sh8*)(&pl[l15 * LDSW + quad * 8]);
        const unsigned short* vb = Vt + ((size_t)kvh * DH + l15) * S_LEN + key0 + quad * 8;
#pragma unroll
        for (int dt = 0; dt < 8; dt++) {
            const sh8 bfv = *(const sh8*)(vb + (size_t)dt * 16 * S_LEN);
            O[dt] = __builtin_amdgcn_mfma_f32_16x16x32_bf16(ap, bfv, O[dt], 0, 0, 0);
        }
    }
#pragma unroll
    for (int r = 0; r < 4; r++) {
        const float inv = 1.0f / lrun[r];
        const int row = q0 + quad * 4 + r;
        float* cp = ctx + (size_t)row * HID_DIM + h * DH;
#pragma unroll
        for (int dt = 0; dt < 8; dt++) cp[dt * 16 + l15] = O[dt][r] * inv;
    }
}

// ============================================================================

extern "C" void kernel_launch(void* const* d_in, const int* in_sizes, int n_in,
                              void* d_out, int out_size, void* d_ws, size_t ws_size,
                              hipStream_t stream)
{
    const float* hidden  = (const float*)d_in[0];
    const int*   pos_ids = (const int*)d_in[2];
    const float* Wq = (const float*)d_in[3];
    const float* Wk = (const float*)d_in[4];
    const float* Wv = (const float*)d_in[5];
    const float* Wo = (const float*)d_in[6];
    const float* prior = (const float*)d_in[7];
    const float* hm1 = (const float*)d_in[8];
    const float* hm2 = (const float*)d_in[9];
    float* out = (float*)d_out;
    char* ws = (char*)d_ws;

    const size_t FAST_NEED = 96485376ull;
    if (ws_size >= FAST_NEED) {
        unsigned short* Wbuf = (unsigned short*)ws;                  // 50,331,648
        unsigned short* Cbf  = (unsigned short*)(ws + 33554432);     // ctx bf16, aliases Wbuf tail in phase 2
        unsigned short* Hbf  = (unsigned short*)(ws + 50331648);     //  8,388,608
        float*          qkv  = (float*)(ws + 58720256);              // 25,165,824
        unsigned short* Qb   = (unsigned short*)(ws + 83886080);     //  8,388,608
        unsigned short* Kb   = (unsigned short*)(ws + 92274688);     //  2,097,152
        unsigned short* Vt   = (unsigned short*)(ws + 94371840);     //  2,097,152
        float*          addv = (float*)(ws + 96468992);              //     16,384

        cvt_hw<<<28672, 256, 0, stream>>>(hidden, Wq, Wk, Wv, Hbf, Wbuf);
        gemm_s<<<dim3(96, 16), 256, 0, stream>>>(Hbf, Wbuf, qkv, 4096, 6144);
        // prep3 tail converts Wo into Wbuf[0:33.5MB] (dead after QKV gemm)
        prep3<<<17168, 256, 0, stream>>>(qkv, pos_ids, prior, Wo, Qb, Kb, Vt, addv, Wbuf);
        attn5<<<dim3(32, 16), 256, 0, stream>>>(Qb, Kb, Vt, addv, hm1, hm2, Cbf);
        gemm_s<<<dim3(64, 16), 256, 0, stream>>>(Cbf, Wbuf, out, 4096, 4096);
    } else {
        float*          qkv = (float*)ws;
        float*          ctx = (float*)(ws + 25165824);
        unsigned short* Qb  = (unsigned short*)(ws + 41943040);
        unsigned short* Kb  = (unsigned short*)(ws + 50331648);
        unsigned short* Vt  = (unsigned short*)(ws + 52428800);
        gemm_bt<<<dim3(48, 8), 256, 0, stream>>>(hidden, Wq, Wk, Wv, 4096, 5120,
                                                 qkv, 1024, 6144, 4096, 6144);
        prep_rope<<<14336, 256, 0, stream>>>(qkv, pos_ids, prior, Qb, Kb, Vt);
        attn_kernel<<<dim3(32, 16), 256, 0, stream>>>(Qb, Kb, Vt, prior, hm1, hm2, ctx);
        gemm_bt<<<dim3(32, 8), 256, 0, stream>>>(ctx, Wo, Wo, Wo, 1 << 30, 1 << 30,
                                                 out, 1024, 4096, 4096, 4096);
    }
}

// Round 8
// 359.342 us; speedup vs baseline: 1.1125x; 1.0814x over previous
//
#include <hip/hip_runtime.h>
#include <math.h>

#define S_LEN 1024
#define HID_DIM 4096
#define NH 32
#define NKV 8
#define DH 128

typedef __attribute__((ext_vector_type(8))) short sh8;
typedef __attribute__((ext_vector_type(4))) short sh4;
typedef __attribute__((ext_vector_type(4))) float f4;

__device__ __forceinline__ unsigned short f2bf(float x) {
    union { float f; unsigned int u; } v; v.f = x;
    unsigned int r = v.u + 0x7FFFu + ((v.u >> 16) & 1u);
    return (unsigned short)(r >> 16);
}

__device__ __forceinline__ void gl_lds16(const unsigned short* g, unsigned short* l) {
    __builtin_amdgcn_global_load_lds(
        (const __attribute__((address_space(1))) unsigned int*)g,
        (__attribute__((address_space(3))) unsigned int*)l, 16, 0, 0);
}

// ============================ FAST PATH =====================================

// cvt_hw v2: hidden->bf16, Wq/Wk/Wv->bf16 (unchanged), PLUS grid tail
// computing the RoPE cos/sin tables (65536 sincos, once) and addvT.
__global__ void cvt_hw(const float* __restrict__ hidden, const float* __restrict__ Wq,
                       const float* __restrict__ Wk, const float* __restrict__ Wv,
                       const float* __restrict__ prior,
                       unsigned short* __restrict__ hbf, unsigned short* __restrict__ wbuf,
                       float* __restrict__ cosT, float* __restrict__ sinT,
                       float* __restrict__ addvT)
{
    const int idx = blockIdx.x * 256 + threadIdx.x;
    const int NH4 = (S_LEN * HID_DIM) / 4;          // 1,048,576
    const int NW4 = (6144 * HID_DIM) / 4;           // 6,291,456
    if (idx < NH4 + NW4) {
        float4 v;
        sh4* dst;
        if (idx < NH4) {
            v = ((const float4*)hidden)[idx];
            dst = (sh4*)hbf + idx;
        } else {
            const int j = idx - NH4;
            const int row = j >> 10;
            if (row < 4096)      v = ((const float4*)Wq)[j];
            else if (row < 5120) v = ((const float4*)Wk)[j - 4096 * 1024];
            else                 v = ((const float4*)Wv)[j - 5120 * 1024];
            dst = (sh4*)wbuf + j;
        }
        sh4 o;
        o.x = (short)f2bf(v.x); o.y = (short)f2bf(v.y);
        o.z = (short)f2bf(v.z); o.w = (short)f2bf(v.w);
        *dst = o;
    } else if (idx < NH4 + NW4 + S_LEN * 64) {      // rope tables
        const int j2 = idx - (NH4 + NW4);
        const int s = j2 >> 6;
        const int i = j2 & 63;
        const float invf = exp2f(-13.287712379549449f * (i * 0.015625f));
        const float ph = (float)s * invf;            // pos_ids == arange(S)
        cosT[j2] = cosf(ph);
        sinT[j2] = sinf(ph);
    } else {                                         // addvT (4 combos)
        const int j3 = idx - (NH4 + NW4 + S_LEN * 64);
        if (j3 < 4 * S_LEN) {
            const int c = j3 >> 10;
            const int s = j3 & 1023;
            const float p = prior[s];
            const float bias = fminf(fmaxf(p, -5.0f), 5.0f);
            float v = 0.0f;
            if (c & 1) v += bias;
            if (c & 2) v += log1pf(0.5f * p);
            addvT[j3] = v * 1.4426950408889634f;
        }
    }
}

// bf16 GEMM v6 (frozen: 78us best across BK/tile/wait sweeps R0-R7):
// 64x128 tile, BK=64, r6 swizzle, single-barrier dbuf, gl_lds16. Wo GEMM.
__global__ __launch_bounds__(256)
void gemm_t(const unsigned short* __restrict__ A, const unsigned short* __restrict__ B,
            float* __restrict__ C, int K, int ldc)
{
    __shared__ __attribute__((aligned(16))) unsigned short sA[2][2][64 * 32];
    __shared__ __attribute__((aligned(16))) unsigned short sB[2][2][128 * 32];

    const int tid  = threadIdx.x;
    const int wave = tid >> 6;
    const int lane = tid & 63;
    const int l15  = lane & 15;
    const int quad = lane >> 4;
    const int m0   = blockIdx.y * 64;
    const int n0   = blockIdx.x * 128;
    const int wm   = (wave >> 1) * 32;
    const int wn   = (wave & 1) * 64;

    const int sslot = (lane & 7) ^ ((lane >> 3) & 7);
    const int srow  = 2 * (lane >> 3) + (sslot >> 2);
    const int scol  = (sslot & 3) * 8;

    const unsigned short* Ag  = A + (size_t)(m0 + 16 * wave + srow) * K + scol;
    const unsigned short* Bg1 = B + (size_t)(n0 + 16 * wave + srow) * K + scol;
    const unsigned short* Bg2 = B + (size_t)(n0 + 64 + 16 * wave + srow) * K + scol;

    f4 acc[2][4];
#pragma unroll
    for (int i = 0; i < 2; i++)
#pragma unroll
        for (int j = 0; j < 4; j++)
            acc[i][j] = f4{0.0f, 0.0f, 0.0f, 0.0f};

    const int rphys = ((((l15 & 1) << 2) + quad) ^ (l15 >> 1)) * 8;

#pragma unroll
    for (int s = 0; s < 2; s++) {
        gl_lds16(Ag + 32 * s,  &sA[0][s][wave * 512]);
        gl_lds16(Bg1 + 32 * s, &sB[0][s][wave * 512]);
        gl_lds16(Bg2 + 32 * s, &sB[0][s][2048 + wave * 512]);
    }

    for (int k0 = 0; k0 < K; k0 += 64) {
        const int cur = (k0 >> 6) & 1;
        __syncthreads();
        const int k1 = k0 + 64;
        if (k1 < K) {
#pragma unroll
            for (int s = 0; s < 2; s++) {
                gl_lds16(Ag + k1 + 32 * s,  &sA[cur ^ 1][s][wave * 512]);
                gl_lds16(Bg1 + k1 + 32 * s, &sB[cur ^ 1][s][wave * 512]);
                gl_lds16(Bg2 + k1 + 32 * s, &sB[cur ^ 1][s][2048 + wave * 512]);
            }
        }

#pragma unroll
        for (int s = 0; s < 2; s++) {
            sh8 af[2], bf[4];
#pragma unroll
            for (int i = 0; i < 2; i++)
                af[i] = *(const sh8*)(&sA[cur][s][((wm + i * 16 + l15) >> 1) * 64 + rphys]);
#pragma unroll
            for (int j = 0; j < 4; j++)
                bf[j] = *(const sh8*)(&sB[cur][s][((wn + j * 16 + l15) >> 1) * 64 + rphys]);
#pragma unroll
            for (int i = 0; i < 2; i++)
#pragma unroll
                for (int j = 0; j < 4; j++)
                    acc[i][j] = __builtin_amdgcn_mfma_f32_16x16x32_bf16(af[i], bf[j], acc[i][j], 0, 0, 0);
        }
    }

#pragma unroll
    for (int i = 0; i < 2; i++) {
        const int mrow = m0 + wm + i * 16 + quad * 4;
#pragma unroll
        for (int j = 0; j < 4; j++) {
            const int ncol = n0 + wn + j * 16 + l15;
#pragma unroll
            for (int r = 0; r < 4; r++)
                C[(size_t)(mrow + r) * ldc + ncol] = acc[i][j][r];
        }
    }
}

// gemm_e: v6 K-loop (byte-identical staging/read/MFMA) + FUSED epilogue.
// The 64x128 tile spans exactly one head (cols bx*128..+127), so the RoPE
// pair (i, i+64) is tile-local. Epilogue: stage acc tile to LDS [64][130]
// fp32 (pad 2 so V's column reads are 2-way not 32-way), barrier, then:
//   bx<32:  Q head  -> rope (table cos/sin) * (log2e/sqrt(128)) -> Qb bf16
//   bx<40:  K kvh   -> rope * gamma(prior)                      -> Kb bf16
//   else:   V kvh   -> eta(prior), transposed                   -> Vt bf16
// Deletes the qkv fp32 buffer (24.5MB write + 25MB read) and prep3's launch.
// LDS pool 48KB unioned (K-loop buffers 48KB, epilogue tile 33.3KB).
__global__ __launch_bounds__(256)
void gemm_e(const unsigned short* __restrict__ A, const unsigned short* __restrict__ B,
            const float* __restrict__ prior,
            const float* __restrict__ cosT, const float* __restrict__ sinT,
            unsigned short* __restrict__ Qb, unsigned short* __restrict__ Kb,
            unsigned short* __restrict__ Vt, int K)
{
    __shared__ __attribute__((aligned(16))) unsigned short smem[24576]; // 48KB
#define SA_(b,s) (smem + ((b) * 2 + (s)) * 2048)
#define SB_(b,s) (smem + 8192 + ((b) * 2 + (s)) * 4096)

    const int tid  = threadIdx.x;
    const int wave = tid >> 6;
    const int lane = tid & 63;
    const int l15  = lane & 15;
    const int quad = lane >> 4;
    const int m0   = blockIdx.y * 64;
    const int n0   = blockIdx.x * 128;
    const int wm   = (wave >> 1) * 32;
    const int wn   = (wave & 1) * 64;

    const int sslot = (lane & 7) ^ ((lane >> 3) & 7);
    const int srow  = 2 * (lane >> 3) + (sslot >> 2);
    const int scol  = (sslot & 3) * 8;

    const unsigned short* Ag  = A + (size_t)(m0 + 16 * wave + srow) * K + scol;
    const unsigned short* Bg1 = B + (size_t)(n0 + 16 * wave + srow) * K + scol;
    const unsigned short* Bg2 = B + (size_t)(n0 + 64 + 16 * wave + srow) * K + scol;

    f4 acc[2][4];
#pragma unroll
    for (int i = 0; i < 2; i++)
#pragma unroll
        for (int j = 0; j < 4; j++)
            acc[i][j] = f4{0.0f, 0.0f, 0.0f, 0.0f};

    const int rphys = ((((l15 & 1) << 2) + quad) ^ (l15 >> 1)) * 8;

#pragma unroll
    for (int s = 0; s < 2; s++) {
        gl_lds16(Ag + 32 * s,  SA_(0, s) + wave * 512);
        gl_lds16(Bg1 + 32 * s, SB_(0, s) + wave * 512);
        gl_lds16(Bg2 + 32 * s, SB_(0, s) + 2048 + wave * 512);
    }

    for (int k0 = 0; k0 < K; k0 += 64) {
        const int cur = (k0 >> 6) & 1;
        __syncthreads();
        const int k1 = k0 + 64;
        if (k1 < K) {
#pragma unroll
            for (int s = 0; s < 2; s++) {
                gl_lds16(Ag + k1 + 32 * s,  SA_(cur ^ 1, s) + wave * 512);
                gl_lds16(Bg1 + k1 + 32 * s, SB_(cur ^ 1, s) + wave * 512);
                gl_lds16(Bg2 + k1 + 32 * s, SB_(cur ^ 1, s) + 2048 + wave * 512);
            }
        }

#pragma unroll
        for (int s = 0; s < 2; s++) {
            sh8 af[2], bf[4];
#pragma unroll
            for (int i = 0; i < 2; i++)
                af[i] = *(const sh8*)(SA_(cur, s) + ((wm + i * 16 + l15) >> 1) * 64 + rphys);
#pragma unroll
            for (int j = 0; j < 4; j++)
                bf[j] = *(const sh8*)(SB_(cur, s) + ((wn + j * 16 + l15) >> 1) * 64 + rphys);
#pragma unroll
            for (int i = 0; i < 2; i++)
#pragma unroll
                for (int j = 0; j < 4; j++)
                    acc[i][j] = __builtin_amdgcn_mfma_f32_16x16x32_bf16(af[i], bf[j], acc[i][j], 0, 0, 0);
        }
    }

    // ---- fused epilogue ----
    float* tl = (float*)smem;                        // [64][130] fp32, 33.3KB
    __syncthreads();                                 // K-loop LDS reads done
#pragma unroll
    for (int i = 0; i < 2; i++) {
        const int row = wm + i * 16 + quad * 4;
#pragma unroll
        for (int j = 0; j < 4; j++) {
            const int col = wn + j * 16 + l15;
#pragma unroll
            for (int r = 0; r < 4; r++)
                tl[(row + r) * 130 + col] = acc[i][j][r];
        }
    }
    __syncthreads();

    const int bx = blockIdx.x;
    if (bx < NH + NKV) {                             // Q or K: rope path
        const int i  = tid & 63;
        const int rg = tid >> 6;
        const bool isQ = (bx < NH);
        const float scQ = 0.08838834764831845f * 1.4426950408889634f; // log2e/sqrt(128)
        unsigned short* dst = isQ
            ? Qb + ((size_t)bx * S_LEN + m0) * DH
            : Kb + ((size_t)(bx - NH) * S_LEN + m0) * DH;
#pragma unroll 4
        for (int rr = 0; rr < 16; rr++) {
            const int srel = rg * 16 + rr;
            const int s    = m0 + srel;
            const float x1 = tl[srel * 130 + i];
            const float x2 = tl[srel * 130 + i + 64];
            const float c  = cosT[s * 64 + i];
            const float sn = sinT[s * 64 + i];
            const float g  = isQ ? scQ
                                 : fminf(fmaxf(1.0f + 0.5f * prior[s], 0.5f), 2.0f);
            unsigned short* q = dst + (size_t)srel * DH;
            q[i]      = f2bf((x1 * c - x2 * sn) * g);
            q[i + 64] = f2bf((x2 * c + x1 * sn) * g);
        }
    } else {                                         // V: eta + transpose
        const int kvh = bx - NH - NKV;
        const int d   = tid >> 1;
        const int sh_ = (tid & 1) * 32;
        unsigned short* vrow = Vt + ((size_t)kvh * DH + d) * S_LEN + m0 + sh_;
#pragma unroll
        for (int b = 0; b < 4; b++) {
            sh8 v8;
#pragma unroll
            for (int e = 0; e < 8; e++) {
                const int srel = sh_ + b * 8 + e;
                const float eta = fminf(fmaxf(1.0f + 0.5f * prior[m0 + srel], 0.5f), 2.0f);
                v8[e] = (short)f2bf(tl[srel * 130 + d] * eta);
            }
            *(sh8*)(vrow + b * 8) = v8;
        }
    }
#undef SA_
#undef SB_
}

// Flash GQA attention (staged, proven) + Wo-convert co-blocks: bx>=32 blocks
// stream Wo fp32->bf16 into Wob (overlaps attention's latency-bound phases;
// replaces prep3's Wo tail). Attention blocks unchanged. LDS 37KB.
__global__ __launch_bounds__(256)
void attn5(const unsigned short* __restrict__ Qb, const unsigned short* __restrict__ Kb,
           const unsigned short* __restrict__ Vt, const float* __restrict__ addvT,
           const float* __restrict__ hm1, const float* __restrict__ hm2,
           const float* __restrict__ Wo, unsigned short* __restrict__ Wob,
           unsigned short* __restrict__ ctx)
{
    __shared__ __attribute__((aligned(16))) unsigned short sK[2][32 * 128]; // [key][d] swz r&7
    __shared__ __attribute__((aligned(16))) unsigned short sV[2][128 * 32]; // [d][key] swz r&3
    __shared__ __attribute__((aligned(16))) short sP[4][16 * 40];

    if (blockIdx.x >= 32) {                          // Wo-convert co-blocks
        const int gid = ((blockIdx.x - 32) * gridDim.y + blockIdx.y) * 256 + threadIdx.x;
        const int NT  = 64 * 16 * 256;               // 262,144 threads
#pragma unroll
        for (int m = 0; m < 16; m++) {
            const int j = m * NT + gid;              // 4,194,304 float4s total
            const float4 v = ((const float4*)Wo)[j];
            sh4 o;
            o.x = (short)f2bf(v.x); o.y = (short)f2bf(v.y);
            o.z = (short)f2bf(v.z); o.w = (short)f2bf(v.w);
            ((sh4*)Wob)[j] = o;
        }
        return;
    }

    const int h    = blockIdx.x;
    const int qb   = (gridDim.y - 1) - blockIdx.y;   // longest blocks first
    const int tid  = threadIdx.x;
    const int wave = tid >> 6;
    const int lane = tid & 63;
    const int l15  = lane & 15;
    const int quad = lane >> 4;
    const int q0   = qb * 64 + wave * 16;
    const int kvh  = h >> 2;
    const int combo = (hm1[h] > 0.5f ? 1 : 0) + (hm2[h] > 0.5f ? 2 : 0);
    const float* av = addvT + combo * S_LEN;

    const unsigned short* ksrcE = Kb + ((size_t)kvh * S_LEN + (lane >> 4)) * DH
                                  + (((lane & 15) ^ (lane >> 4)) * 8);
    const unsigned short* ksrcO = Kb + ((size_t)kvh * S_LEN + (lane >> 4)) * DH
                                  + (((lane & 15) ^ (4 + (lane >> 4))) * 8);
    const unsigned short* vsrc0 = Vt + ((size_t)kvh * DH + (lane >> 2)) * S_LEN
                                  + (((lane & 3) ^ ((lane >> 2) & 3)) * 8);

    auto stage = [&](int c, int buf) {
        const int k0 = c * 32;
        if (wave < 2) {
#pragma unroll
            for (int j = 0; j < 4; j++) {
                const int i = wave * 4 + j;
                const unsigned short* src = (j & 1) ? ksrcO : ksrcE;
                gl_lds16(src + (size_t)(k0 + 4 * i) * DH, &sK[buf][i * 512]);
            }
        } else {
#pragma unroll
            for (int j = 0; j < 4; j++) {
                const int i = (wave - 2) * 4 + j;
                gl_lds16(vsrc0 + (size_t)(16 * i) * S_LEN + k0, &sV[buf][i * 512]);
            }
        }
    };

    sh8 qf[4];
    {
        const unsigned short* qbase = Qb + ((size_t)h * S_LEN + q0 + l15) * DH + quad * 8;
#pragma unroll
        for (int kc = 0; kc < 4; kc++)
            qf[kc] = *(const sh8*)(qbase + kc * 32);
    }

    f4 O[8];
#pragma unroll
    for (int dt = 0; dt < 8; dt++) O[dt] = f4{0.0f, 0.0f, 0.0f, 0.0f};
    float lrun[4] = {0.0f, 0.0f, 0.0f, 0.0f};

    short* pl = &sP[wave][0];
    const int sw = l15 & 7;
    const int sv = l15 & 3;
    const int nch = 2 * qb + 2;

    stage(0, 0);                               // prologue

    for (int c = 0; c < nch; c++) {
        const int cur = c & 1;
        const int k0 = c * 32;
        __syncthreads();                       // buf[cur] landed; buf[cur^1] free
        if (c + 1 < nch) stage(c + 1, cur ^ 1);

#pragma unroll
        for (int t = 0; t < 2; t++) {
            f4 a = f4{0.0f, 0.0f, 0.0f, 0.0f};
            __builtin_amdgcn_s_setprio(1);
#pragma unroll
            for (int kc = 0; kc < 4; kc++) {
                const sh8 kfr = *(const sh8*)(&sK[cur][(t * 16 + l15) * 128 + ((kc * 4 + quad) ^ sw) * 8]);
                a = __builtin_amdgcn_mfma_f32_16x16x32_bf16(qf[kc], kfr, a, 0, 0, 0);
            }
            __builtin_amdgcn_s_setprio(0);
            const int key = k0 + t * 16 + l15;
            const float ad = av[key];
#pragma unroll
            for (int r = 0; r < 4; r++) {
                const int qrow = q0 + quad * 4 + r;
                float ex = exp2f(a[r] + ad);
                ex = (key <= qrow) ? ex : 0.0f;
                lrun[r] += ex;
                pl[(quad * 4 + r) * 40 + t * 16 + l15] = (short)f2bf(ex);
            }
        }
        asm volatile("s_waitcnt lgkmcnt(0)" ::: "memory");
        const sh8 ap = *(const sh8*)(&pl[l15 * 40 + quad * 8]);
        __builtin_amdgcn_s_setprio(1);
#pragma unroll
        for (int dt = 0; dt < 8; dt++) {
            const sh8 vfr = *(const sh8*)(&sV[cur][(dt * 16 + l15) * 32 + (quad ^ sv) * 8]);
            O[dt] = __builtin_amdgcn_mfma_f32_16x16x32_bf16(ap, vfr, O[dt], 0, 0, 0);
        }
        __builtin_amdgcn_s_setprio(0);
    }

#pragma unroll
    for (int r = 0; r < 4; r++) {
        float l = lrun[r];
        l += __shfl_xor(l, 1); l += __shfl_xor(l, 2);
        l += __shfl_xor(l, 4); l += __shfl_xor(l, 8);
        const float inv = 1.0f / l;
        const int row = q0 + quad * 4 + r;
        unsigned short* cp = ctx + (size_t)row * HID_DIM + h * DH;
#pragma unroll
        for (int dt = 0; dt < 8; dt++)
            cp[dt * 16 + l15] = f2bf(O[dt][r] * inv);
    }
}

// ========================= FALLBACK (round-1, proven @54.5MB) ===============

#define LDSW 40

__global__ __launch_bounds__(256)
void gemm_bt(const float* __restrict__ A,
             const float* __restrict__ B0, const float* __restrict__ B1,
             const float* __restrict__ B2, int n_b1, int n_b2,
             float* __restrict__ C, int M, int N, int K, int ldc)
{
    __shared__ __attribute__((aligned(16))) short sA[128 * LDSW];
    __shared__ __attribute__((aligned(16))) short sB[128 * LDSW];
    const int tid  = threadIdx.x;
    const int m0   = blockIdx.y * 128;
    const int n0   = blockIdx.x * 128;
    const float* Bp = B0; int nloc = n0;
    if (n0 >= n_b2)      { Bp = B2; nloc = n0 - n_b2; }
    else if (n0 >= n_b1) { Bp = B1; nloc = n0 - n_b1; }
    const int wave = tid >> 6, lane = tid & 63;
    const int l15 = lane & 15, quad = lane >> 4;
    const int wm = (wave >> 1) * 64, wn = (wave & 1) * 64;
    const int rb = tid >> 3, c4 = (tid & 7) * 4;
    f4 acc[4][4];
#pragma unroll
    for (int i = 0; i < 4; i++)
#pragma unroll
        for (int j = 0; j < 4; j++) acc[i][j] = f4{0.0f, 0.0f, 0.0f, 0.0f};
    for (int k0 = 0; k0 < K; k0 += 32) {
        __syncthreads();
#pragma unroll
        for (int i = 0; i < 4; i++) {
            const int row = rb + 32 * i;
            const float4 va = *(const float4*)(A  + (size_t)(m0 + row) * K + k0 + c4);
            const float4 vb = *(const float4*)(Bp + (size_t)(nloc + row) * K + k0 + c4);
            sh4 sa, sb;
            sa.x = (short)f2bf(va.x); sa.y = (short)f2bf(va.y);
            sa.z = (short)f2bf(va.z); sa.w = (short)f2bf(va.w);
            sb.x = (short)f2bf(vb.x); sb.y = (short)f2bf(vb.y);
            sb.z = (short)f2bf(vb.z); sb.w = (short)f2bf(vb.w);
            *(sh4*)(&sA[row * LDSW + c4]) = sa;
            *(sh4*)(&sB[row * LDSW + c4]) = sb;
        }
        __syncthreads();
        sh8 af[4], bf[4];
#pragma unroll
        for (int i = 0; i < 4; i++) af[i] = *(const sh8*)(&sA[(wm + i * 16 + l15) * LDSW + quad * 8]);
#pragma unroll
        for (int j = 0; j < 4; j++) bf[j] = *(const sh8*)(&sB[(wn + j * 16 + l15) * LDSW + quad * 8]);
#pragma unroll
        for (int i = 0; i < 4; i++)
#pragma unroll
            for (int j = 0; j < 4; j++)
                acc[i][j] = __builtin_amdgcn_mfma_f32_16x16x32_bf16(af[i], bf[j], acc[i][j], 0, 0, 0);
    }
#pragma unroll
    for (int i = 0; i < 4; i++) {
        const int mrow = m0 + wm + i * 16 + quad * 4;
#pragma unroll
        for (int j = 0; j < 4; j++) {
            const int ncol = n0 + wn + j * 16 + l15;
#pragma unroll
            for (int r = 0; r < 4; r++)
                C[(size_t)(mrow + r) * ldc + ncol] = acc[i][j][r];
        }
    }
}

__global__ void prep_rope(const float* __restrict__ qkv, const int* __restrict__ pos_ids,
                          const float* __restrict__ prior,
                          unsigned short* __restrict__ Qb, unsigned short* __restrict__ Kb,
                          unsigned short* __restrict__ Vt)
{
    const int idx = blockIdx.x * blockDim.x + threadIdx.x;
    const int NQ = S_LEN * 40 * 64;
    if (idx < NQ) {
        const int s = idx / (40 * 64);
        const int rem = idx % (40 * 64);
        const int hh = rem >> 6, i = rem & 63;
        const float pos = (float)pos_ids[s];
        const float invf = exp2f(-13.287712379549449f * (i * 0.015625f));
        const float ph = pos * invf;
        const float c = cosf(ph), sn = sinf(ph);
        if (hh < NH) {
            const float* base = qkv + (size_t)s * 6144 + hh * 128;
            const float x1 = base[i], x2 = base[i + 64];
            const float sc = 0.08838834764831845f;
            unsigned short* q = Qb + ((size_t)hh * S_LEN + s) * DH;
            q[i] = f2bf((x1 * c - x2 * sn) * sc);
            q[i + 64] = f2bf((x2 * c + x1 * sn) * sc);
        } else {
            const int kvh = hh - NH;
            const float* base = qkv + (size_t)s * 6144 + 4096 + kvh * 128;
            const float p = prior[s];
            const float gamma = fminf(fmaxf(1.0f + 0.5f * p, 0.5f), 2.0f);
            const float x1 = base[i], x2 = base[i + 64];
            unsigned short* kp = Kb + ((size_t)kvh * S_LEN + s) * DH;
            kp[i] = f2bf((x1 * c - x2 * sn) * gamma);
            kp[i + 64] = f2bf((x2 * c + x1 * sn) * gamma);
        }
    } else {
        const int j = idx - NQ;
        if (j < S_LEN * NKV * DH) {
            const int s = j / (NKV * DH);
            const int rem = j % (NKV * DH);
            const int kvh = rem >> 7, d = rem & 127;
            const float p = prior[s];
            const float eta = fminf(fmaxf(1.0f + 0.5f * p, 0.5f), 2.0f);
            const float val = qkv[(size_t)s * 6144 + 5120 + kvh * 128 + d] * eta;
            Vt[((size_t)kvh * DH + d) * S_LEN + s] = f2bf(val);
        }
    }
}

__global__ __launch_bounds__(256)
void attn_kernel(const unsigned short* __restrict__ Qb, const unsigned short* __restrict__ Kb,
                 const unsigned short* __restrict__ Vt, const float* __restrict__ prior,
                 const float* __restrict__ hm1, const float* __restrict__ hm2,
                 float* __restrict__ ctx)
{
    __shared__ __attribute__((aligned(16))) short p_lds[4][16 * LDSW];
    const int h = blockIdx.x, qb = blockIdx.y;
    const int wave = threadIdx.x >> 6, lane = threadIdx.x & 63;
    const int l15 = lane & 15, quad = lane >> 4;
    const int q0 = qb * 64 + wave * 16;
    const int kvh = h >> 2;
    const float m1 = hm1[h], m2 = hm2[h];
    const float NEG = -3.0e38f;
    sh8 qf[4];
    {
        const unsigned short* qbase = Qb + ((size_t)h * S_LEN + q0 + l15) * DH + quad * 8;
#pragma unroll
        for (int kc = 0; kc < 4; kc++) qf[kc] = *(const sh8*)(qbase + kc * 32);
    }
    f4 O[8];
#pragma unroll
    for (int dt = 0; dt < 8; dt++) O[dt] = f4{0.0f, 0.0f, 0.0f, 0.0f};
    float mrun[4], lrun[4];
#pragma unroll
    for (int r = 0; r < 4; r++) { mrun[r] = NEG; lrun[r] = 0.0f; }
    short* pl = &p_lds[wave][0];
    const int qmax = q0 + 15;
    for (int key0 = 0; key0 <= qmax; key0 += 32) {
        float sc[2][4];
#pragma unroll
        for (int t = 0; t < 2; t++) {
            const int kt = key0 + t * 16;
            const unsigned short* kb = Kb + ((size_t)kvh * S_LEN + kt + l15) * DH + quad * 8;
            f4 a = f4{0.0f, 0.0f, 0.0f, 0.0f};
#pragma unroll
            for (int kc = 0; kc < 4; kc++) {
                const sh8 bfr = *(const sh8*)(kb + kc * 32);
                a = __builtin_amdgcn_mfma_f32_16x16x32_bf16(qf[kc], bfr, a, 0, 0, 0);
            }
            const int key = kt + l15;
            const float p = prior[key];
            const float bias = fminf(fmaxf(p, -5.0f), 5.0f);
            const float addv = m1 * bias + m2 * logf(1.0f + 0.5f * p);
#pragma unroll
            for (int r = 0; r < 4; r++) {
                const int qrow = q0 + quad * 4 + r;
                sc[t][r] = (key <= qrow) ? (a[r] + addv) : NEG;
            }
        }
        float cm[4], mnew[4], alpha[4], rs[4];
#pragma unroll
        for (int r = 0; r < 4; r++) {
            cm[r] = fmaxf(sc[0][r], sc[1][r]);
            cm[r] = fmaxf(cm[r], __shfl_xor(cm[r], 1));
            cm[r] = fmaxf(cm[r], __shfl_xor(cm[r], 2));
            cm[r] = fmaxf(cm[r], __shfl_xor(cm[r], 4));
            cm[r] = fmaxf(cm[r], __shfl_xor(cm[r], 8));
            mnew[r] = fmaxf(mrun[r], cm[r]);
            alpha[r] = expf(mrun[r] - mnew[r]);
        }
        float e[2][4];
#pragma unroll
        for (int t = 0; t < 2; t++)
#pragma unroll
            for (int r = 0; r < 4; r++) e[t][r] = expf(sc[t][r] - mnew[r]);
#pragma unroll
        for (int r = 0; r < 4; r++) {
            rs[r] = e[0][r] + e[1][r];
            rs[r] += __shfl_xor(rs[r], 1); rs[r] += __shfl_xor(rs[r], 2);
            rs[r] += __shfl_xor(rs[r], 4); rs[r] += __shfl_xor(rs[r], 8);
            lrun[r] = lrun[r] * alpha[r] + rs[r];
            mrun[r] = mnew[r];
        }
#pragma unroll
        for (int dt = 0; dt < 8; dt++)
#pragma unroll
            for (int r = 0; r < 4; r++) O[dt][r] *= alpha[r];
#pragma unroll
        for (int t = 0; t < 2; t++)
#pragma unroll
            for (int r = 0; r < 4; r++)
                pl[(quad * 4 + r) * LDSW + t * 16 + l15] = (short)f2bf(e[t][r]);
        asm volatile("s_waitcnt lgkmcnt(0)" ::: "memory");
        const sh8 ap = *(const sh8*)(&pl[l15 * LDSW + quad * 8]);
        const unsigned short* vb = Vt + ((size_t)kvh * DH + l15) * S_LEN + key0 + quad * 8;
#pragma unroll
        for (int dt = 0; dt < 8; dt++) {
            const sh8 bfv = *(const sh8*)(vb + (size_t)dt * 16 * S_LEN);
            O[dt] = __builtin_amdgcn_mfma_f32_16x16x32_bf16(ap, bfv, O[dt], 0, 0, 0);
        }
    }
#pragma unroll
    for (int r = 0; r < 4; r++) {
        const float inv = 1.0f / lrun[r];
        const int row = q0 + quad * 4 + r;
        float* cp = ctx + (size_t)row * HID_DIM + h * DH;
#pragma unroll
        for (int dt = 0; dt < 8; dt++) cp[dt * 16 + l15] = O[dt][r] * inv;
    }
}

// ============================================================================

extern "C" void kernel_launch(void* const* d_in, const int* in_sizes, int n_in,
                              void* d_out, int out_size, void* d_ws, size_t ws_size,
                              hipStream_t stream)
{
    const float* hidden  = (const float*)d_in[0];
    const int*   pos_ids = (const int*)d_in[2];
    const float* Wq = (const float*)d_in[3];
    const float* Wk = (const float*)d_in[4];
    const float* Wv = (const float*)d_in[5];
    const float* Wo = (const float*)d_in[6];
    const float* prior = (const float*)d_in[7];
    const float* hm1 = (const float*)d_in[8];
    const float* hm2 = (const float*)d_in[9];
    float* out = (float*)d_out;
    char* ws = (char*)d_ws;

    const size_t FAST_NEED = 96485376ull;
    if (ws_size >= FAST_NEED) {
        unsigned short* Wbuf = (unsigned short*)ws;                  // 50.3MB W_qkv bf16; Wob[0:33.5MB] in phase 2
        unsigned short* Cbf  = (unsigned short*)(ws + 33554432);     // ctx bf16 (aliases dead Wk/Wv bf16)
        unsigned short* Hbf  = (unsigned short*)(ws + 50331648);     // 8.4MB hidden bf16
        float*          cosT = (float*)(ws + 58720256);              // 256KB (freed qkv slot)
        float*          sinT = (float*)(ws + 58982400);              // 256KB
        unsigned short* Qb   = (unsigned short*)(ws + 83886080);     // 8.4MB
        unsigned short* Kb   = (unsigned short*)(ws + 92274688);     // 2.1MB
        unsigned short* Vt   = (unsigned short*)(ws + 94371840);     // 2.1MB
        float*          addv = (float*)(ws + 96468992);              // 16KB

        // 4 launches: prep fused into gemm epilogue + attn co-blocks.
        cvt_hw<<<28944, 256, 0, stream>>>(hidden, Wq, Wk, Wv, prior, Hbf, Wbuf,
                                          cosT, sinT, addv);
        gemm_e<<<dim3(48, 16), 256, 0, stream>>>(Hbf, Wbuf, prior, cosT, sinT,
                                                 Qb, Kb, Vt, 4096);
        attn5<<<dim3(96, 16), 256, 0, stream>>>(Qb, Kb, Vt, addv, hm1, hm2,
                                                Wo, Wbuf, Cbf);
        gemm_t<<<dim3(32, 16), 256, 0, stream>>>(Cbf, Wbuf, out, 4096, 4096);
    } else {
        float*          qkv = (float*)ws;
        float*          ctx = (float*)(ws + 25165824);
        unsigned short* Qb  = (unsigned short*)(ws + 41943040);
        unsigned short* Kb  = (unsigned short*)(ws + 50331648);
        unsigned short* Vt  = (unsigned short*)(ws + 52428800);
        gemm_bt<<<dim3(48, 8), 256, 0, stream>>>(hidden, Wq, Wk, Wv, 4096, 5120,
                                                 qkv, 1024, 6144, 4096, 6144);
        prep_rope<<<14336, 256, 0, stream>>>(qkv, pos_ids, prior, Qb, Kb, Vt);
        attn_kernel<<<dim3(32, 16), 256, 0, stream>>>(Qb, Kb, Vt, prior, hm1, hm2, ctx);
        gemm_bt<<<dim3(32, 8), 256, 0, stream>>>(ctx, Wo, Wo, Wo, 1 << 30, 1 << 30,
                                                 out, 1024, 4096, 4096, 4096);
    }
}